// Round 7
// baseline (586.638 us; speedup 1.0000x reference)
//
#include <hip/hip_runtime.h>

#define USER_NUM 100000
#define ITEM_NUM 150000
#define NTOT     250000           // USER_NUM + ITEM_NUM
#define EMB      64
#define NNZ      5000000
#define NROW_ELEMS (NTOT * EMB)   // 16,000,000 floats = 64 MB
#define NCB      977              // ceil(NTOT/256) coarse buckets of 256 rows
#define NSB      192              // scatter blocks
#define BIGTILE  ((NNZ + NSB - 1) / NSB)       // 26,042 edges per scatter block
#define SCAP     6144             // per-coarse-bucket LDS cap (mean 5120, +14 sigma)
#define PROTO_ELEMS (2048 * 64)   // 131072 floats per prototype array

// ---------------- bf16 helpers (manual RNE pack, shift expand) ---------------
__device__ __forceinline__ unsigned bf1(float x) {
    unsigned u = __float_as_uint(x);
    return (u + 0x7FFFu + ((u >> 16) & 1u)) >> 16;          // RNE
}
__device__ __forceinline__ unsigned pkbf(float a, float b) {
    return bf1(a) | (bf1(b) << 16);
}
__device__ __forceinline__ float bflo(unsigned u) { return __uint_as_float(u << 16); }
__device__ __forceinline__ float bfhi(unsigned u) { return __uint_as_float(u & 0xFFFF0000u); }

// ============================ coarse histogram ===============================
__global__ __launch_bounds__(256) void hist_kernel(const int* __restrict__ rows,
                                                   int* __restrict__ counts) {
    __shared__ int sh[NCB];
    for (int i = threadIdx.x; i < NCB; i += 256) sh[i] = 0;
    __syncthreads();
    int stride = gridDim.x * blockDim.x;
    const int4* rows4 = (const int4*)rows;
    for (int i = blockIdx.x * blockDim.x + threadIdx.x; i < NNZ / 4; i += stride) {
        int4 r = rows4[i];
        atomicAdd(&sh[r.x >> 8], 1);
        atomicAdd(&sh[r.y >> 8], 1);
        atomicAdd(&sh[r.z >> 8], 1);
        atomicAdd(&sh[r.w >> 8], 1);
    }
    __syncthreads();
    for (int i = threadIdx.x; i < NCB; i += 256)
        if (sh[i]) atomicAdd(&counts[i], sh[i]);
}

// exclusive scan over NCB<=1024 counts -> boffs + bcursor; also offs[NTOT]=NNZ
__global__ void scan_kernel(const int* __restrict__ counts, int* __restrict__ boffs,
                            int* __restrict__ bcursor, int* __restrict__ offs) {
    __shared__ int sm[1024];
    int t = threadIdx.x;
    int c = (t < NCB) ? counts[t] : 0;
    sm[t] = c; __syncthreads();
    for (int off = 1; off < 1024; off <<= 1) {
        int v = (t >= off) ? sm[t - off] : 0;
        __syncthreads();
        sm[t] += v;
        __syncthreads();
    }
    if (t < NCB) { boffs[t] = sm[t] - c; bcursor[t] = sm[t] - c; }
    if (t == 1023) { boffs[NCB] = sm[1023]; offs[NTOT] = sm[1023]; }
}

// ================= two-pass counting scatter (in-block combining) ===========
// Each block owns BIGTILE consecutive edges. Pass A: LDS count per coarse
// bucket. Claim one contiguous global run per bucket (~27 edges). Pass B:
// re-read edges, rank via LDS cursor, write. All writes to a run come from
// THIS block -> lines assemble in one XCD's L2; working set ~62 KB/block.
// Packed word: col (bits 0..17) | localrow-in-256 (bits 18..25).
__global__ __launch_bounds__(256) void scatter_2pass(
        const int* __restrict__ rows, const int* __restrict__ cols,
        const float* __restrict__ vals, int* __restrict__ bcursor,
        int2* __restrict__ epk) {
    __shared__ int cnt[NCB];
    __shared__ int base[NCB];
    int t = threadIdx.x;
    int tb = blockIdx.x * BIGTILE;
    int nmax = NNZ - tb; if (nmax > BIGTILE) nmax = BIGTILE;
    if (nmax <= 0) return;                      // uniform per block
    for (int i = t; i < NCB; i += 256) cnt[i] = 0;
    __syncthreads();
    for (int i = t; i < nmax; i += 256)         // pass A: count
        atomicAdd(&cnt[rows[tb + i] >> 8], 1);
    __syncthreads();
    for (int i = t; i < NCB; i += 256) {        // claim contiguous runs
        int c = cnt[i];
        base[i] = c ? atomicAdd(&bcursor[i], c) : 0;
        cnt[i] = 0;                             // reuse as local cursor
    }
    __syncthreads();
    for (int i = t; i < nmax; i += 256) {       // pass B: rank + write
        int r = rows[tb + i];
        int cb = r >> 8;
        int rank = atomicAdd(&cnt[cb], 1);
        unsigned ex = (unsigned)cols[tb + i] | ((unsigned)(r & 255) << 18);
        epk[base[cb] + rank] = make_int2((int)ex, __float_as_int(vals[tb + i]));
    }
}

// ============== per-coarse-bucket in-LDS row sort + CSR offsets ==============
__global__ __launch_bounds__(256) void bucket_sort(const int* __restrict__ boffs,
                                                   int2* __restrict__ epk,
                                                   int* __restrict__ offs) {
    __shared__ int2 se[SCAP];         // 48 KB
    __shared__ int cnt[256];
    __shared__ int base[256];
    __shared__ int cur[256];
    int b = blockIdx.x, t = threadIdx.x;
    int beg = boffs[b], end = boffs[b + 1];
    int n = end - beg; if (n > SCAP) n = SCAP;   // +14 sigma, unreachable
    cnt[t] = 0;
    __syncthreads();
    for (int i = t; i < n; i += 256) {
        int2 e = epk[beg + i];
        se[i] = e;
        atomicAdd(&cnt[(((unsigned)e.x) >> 18) & 0xFFu], 1);
    }
    __syncthreads();
    int c = cnt[t];
    base[t] = c; __syncthreads();
    for (int off = 1; off < 256; off <<= 1) {     // Hillis-Steele inclusive
        int v = (t >= off) ? base[t - off] : 0;
        __syncthreads();
        base[t] += v;
        __syncthreads();
    }
    int mybase = beg + base[t] - c;               // exclusive + global base
    cur[t] = mybase;
    int r = b * 256 + t;
    if (r < NTOT) offs[r] = mybase;
    __syncthreads();
    for (int i = t; i < n; i += 256) {
        int2 e = se[i];
        int lr = (int)((((unsigned)e.x) >> 18) & 0xFFu);
        int p = atomicAdd(&cur[lr], 1);
        epk[p] = make_int2((int)(((unsigned)e.x) & 0x3FFFFu), e.y);
    }
}

// ===================== convert: ego f32 -> bf16 xb, + pass-throughs =========
__global__ __launch_bounds__(256) void convert_kernel(
        const float* __restrict__ ue, const float* __restrict__ ie,
        const float* __restrict__ up, const float* __restrict__ ip,
        ushort* __restrict__ xb, float* __restrict__ out) {
    const int NG = NROW_ELEMS / 8;               // 2,000,000 8-elem groups
    int g = blockIdx.x * blockDim.x + threadIdx.x;
    if (g < NG) {
        int base = g * 8;
        const float* src = (base < USER_NUM * EMB) ? ue + base
                                                   : ie + (base - USER_NUM * EMB);
        float4 a = ((const float4*)src)[0];
        float4 b = ((const float4*)src)[1];
        float4* oc = (float4*)(out + NROW_ELEMS + base);
        oc[0] = a; oc[1] = b;
        uint4 w;
        w.x = pkbf(a.x, a.y); w.y = pkbf(a.z, a.w);
        w.z = pkbf(b.x, b.y); w.w = pkbf(b.z, b.w);
        ((uint4*)xb)[g] = w;
    } else {
        int pj = (g - NG) * 8;
        if (pj < PROTO_ELEMS) {
            float4 a = *(const float4*)(up + pj), b = *(const float4*)(up + pj + 4);
            float4* o = (float4*)(out + 2 * NROW_ELEMS + pj);
            o[0] = a; o[1] = b;
        } else if (pj < 2 * PROTO_ELEMS) {
            int q = pj - PROTO_ELEMS;
            float4 a = *(const float4*)(ip + q), b = *(const float4*)(ip + q + 4);
            float4* o = (float4*)(out + 2 * NROW_ELEMS + PROTO_ELEMS + q);
            o[0] = a; o[1] = b;
        }
    }
}

// ===================== bf16-gather CSR SpMM (no atomics) =====================
// 8 lanes per row; lane l owns dims [8l, 8l+8): one uint4 (8 bf16) per edge.
// LAYER 1,2: acc -> lb (bf16).  LAYER 3: out = (ego0 + l1 + l2 + acc) * 0.25.

__device__ __forceinline__ void acc8(float* acc, float v, uint4 u) {
    acc[0] += v * bflo(u.x); acc[1] += v * bfhi(u.x);
    acc[2] += v * bflo(u.y); acc[3] += v * bfhi(u.y);
    acc[4] += v * bflo(u.z); acc[5] += v * bfhi(u.z);
    acc[6] += v * bflo(u.w); acc[7] += v * bfhi(u.w);
}

template <int LAYER>
__global__ __launch_bounds__(256) void spmm_bf(
        const ushort* __restrict__ xb,       // gather source (bf16, NTOT*64)
        const int* __restrict__ offs, const int2* __restrict__ epk,
        ushort* __restrict__ lb,             // layer output (bf16), LAYER 1/2
        const float* __restrict__ ue, const float* __restrict__ ie,   // LAYER 3
        const ushort* __restrict__ l1b, const ushort* __restrict__ l2b,// LAYER 3
        float* __restrict__ out) {           // LAYER 3
    int t = blockIdx.x * blockDim.x + threadIdx.x;
    int r = t >> 3, l = t & 7;
    if (r >= NTOT) return;
    const uint4* src = (const uint4*)xb;     // 8 uint4 per row
    int beg = offs[r], end = offs[r + 1];
    float acc[8] = {0.f, 0.f, 0.f, 0.f, 0.f, 0.f, 0.f, 0.f};
    int j = beg;
    for (; j + 3 < end; j += 4) {
        int2 e0 = epk[j], e1 = epk[j + 1], e2 = epk[j + 2], e3 = epk[j + 3];
        uint4 u0 = src[e0.x * 8 + l];
        uint4 u1 = src[e1.x * 8 + l];
        uint4 u2 = src[e2.x * 8 + l];
        uint4 u3 = src[e3.x * 8 + l];
        acc8(acc, __int_as_float(e0.y), u0);
        acc8(acc, __int_as_float(e1.y), u1);
        acc8(acc, __int_as_float(e2.y), u2);
        acc8(acc, __int_as_float(e3.y), u3);
    }
    for (; j < end; ++j) {
        int2 e0 = epk[j];
        uint4 u0 = src[e0.x * 8 + l];
        acc8(acc, __int_as_float(e0.y), u0);
    }
    int idx = r * 8 + l;                     // uint4 index into bf16 row space
    if (LAYER == 1 || LAYER == 2) {
        uint4 w;
        w.x = pkbf(acc[0], acc[1]); w.y = pkbf(acc[2], acc[3]);
        w.z = pkbf(acc[4], acc[5]); w.w = pkbf(acc[6], acc[7]);
        ((uint4*)lb)[idx] = w;
    } else {
        int base = r * EMB + l * 8;          // float index
        const float* ep = (r < USER_NUM) ? ue + base
                                         : ie + (base - USER_NUM * EMB);
        float4 ea = ((const float4*)ep)[0];
        float4 eb = ((const float4*)ep)[1];
        uint4 u1 = ((const uint4*)l1b)[idx];
        uint4 u2 = ((const uint4*)l2b)[idx];
        float4 o0, o1;
        o0.x = (ea.x + bflo(u1.x) + bflo(u2.x) + acc[0]) * 0.25f;
        o0.y = (ea.y + bfhi(u1.x) + bfhi(u2.x) + acc[1]) * 0.25f;
        o0.z = (ea.z + bflo(u1.y) + bflo(u2.y) + acc[2]) * 0.25f;
        o0.w = (ea.w + bfhi(u1.y) + bfhi(u2.y) + acc[3]) * 0.25f;
        o1.x = (eb.x + bflo(u1.z) + bflo(u2.z) + acc[4]) * 0.25f;
        o1.y = (eb.y + bfhi(u1.z) + bfhi(u2.z) + acc[5]) * 0.25f;
        o1.z = (eb.z + bflo(u1.w) + bflo(u2.w) + acc[6]) * 0.25f;
        o1.w = (eb.w + bfhi(u1.w) + bfhi(u2.w) + acc[7]) * 0.25f;
        float4* op = (float4*)(out + base);
        op[0] = o0; op[1] = o1;
    }
}

// =============================================================================
extern "C" void kernel_launch(void* const* d_in, const int* in_sizes, int n_in,
                              void* d_out, int out_size, void* d_ws, size_t ws_size,
                              hipStream_t stream) {
    const float* ue   = (const float*)d_in[0];
    const float* ie   = (const float*)d_in[1];
    const float* up   = (const float*)d_in[2];
    const float* ip   = (const float*)d_in[3];
    const float* vals = (const float*)d_in[4];
    const int*   rows = (const int*)d_in[5];
    const int*   cols = (const int*)d_in[6];
    float* out = (float*)d_out;

    // ws layout (4-byte units):
    //   [0, 8M)         xb      : bf16 ego (32 MB); ALIASED as l2b after spmm1
    //   [8M, 16M)       l1b     : bf16 layer-1 (32 MB)
    //   [16M, 26M)      epk     : 5M int2 edges (40 MB)
    //   26,000,000      offs    : NTOT+1 row offsets
    //   26,250,112      boffs   : NCB+1
    //   26,252,000      bcursor : NCB
    //   26,253,000      bcounts : NCB
    ushort* xb     = (ushort*)d_ws;                  // also l2b (dead after spmm1)
    ushort* l1b    = (ushort*)((int*)d_ws + 8000000);
    int2*   epk    = (int2*)((int*)d_ws + 16000000);
    int*    offs   = (int*)d_ws + 26000000;
    int*    boffs  = (int*)d_ws + 26250112;
    int*    bcursor= (int*)d_ws + 26252000;
    int*    bcounts= (int*)d_ws + 26253000;
    ushort* l2b    = xb;

    const int sgrid = (NTOT * 8 + 255) / 256;        // 7813
    const int cgrid = (NROW_ELEMS / 8 + 2 * PROTO_ELEMS / 8 + 255) / 256;

    // ---- build row-sorted CSR (2-pass counting scatter + LDS sort) ----
    hipMemsetAsync(bcounts, 0, NCB * sizeof(int), stream);
    hist_kernel  <<<256, 256, 0, stream>>>(rows, bcounts);
    scan_kernel  <<<1, 1024, 0, stream>>>(bcounts, boffs, bcursor, offs);
    scatter_2pass<<<NSB, 256, 0, stream>>>(rows, cols, vals, bcursor, epk);
    bucket_sort  <<<NCB, 256, 0, stream>>>(boffs, epk, offs);

    // ---- convert ego to bf16 + all f32 pass-through copies ----
    convert_kernel<<<cgrid, 256, 0, stream>>>(ue, ie, up, ip, xb, out);

    // ---- 3 bf16-gather SpMM layers; f32 assembly in layer 3 ----
    spmm_bf<1><<<sgrid, 256, 0, stream>>>(xb,  offs, epk, l1b,
                                          nullptr, nullptr, nullptr, nullptr, nullptr);
    spmm_bf<2><<<sgrid, 256, 0, stream>>>(l1b, offs, epk, l2b,
                                          nullptr, nullptr, nullptr, nullptr, nullptr);
    spmm_bf<3><<<sgrid, 256, 0, stream>>>(l2b, offs, epk, nullptr,
                                          ue, ie, l1b, l2b, out);
}

// Round 8
// 543.937 us; speedup vs baseline: 1.0785x; 1.0785x over previous
//
#include <hip/hip_runtime.h>

#define USER_NUM 100000
#define ITEM_NUM 150000
#define NTOT     250000           // USER_NUM + ITEM_NUM
#define EMB      64
#define NNZ      5000000
#define NROW_ELEMS (NTOT * EMB)   // 16,000,000 floats = 64 MB
#define NCB      977              // ceil(NTOT/256) sub-buckets of 256 rows
#define NSUP     62               // ceil(NTOT/4096) super-buckets of 4096 rows
#define NSB1     1024             // part1 blocks
#define T1       4884             // edges per part1 block (mult of 4; 1024*4884 >= NNZ)
#define G2       16               // chunks per super-bucket in part2
#define SCAP     6144             // per-sub-bucket LDS cap (mean 5120, +14 sigma)
#define PROTO_ELEMS (2048 * 64)   // 131072 floats per prototype array

// ---------------- bf16 helpers (manual RNE pack, shift expand) ---------------
__device__ __forceinline__ unsigned bf1(float x) {
    unsigned u = __float_as_uint(x);
    return (u + 0x7FFFu + ((u >> 16) & 1u)) >> 16;          // RNE
}
__device__ __forceinline__ unsigned pkbf(float a, float b) {
    return bf1(a) | (bf1(b) << 16);
}
__device__ __forceinline__ float bflo(unsigned u) { return __uint_as_float(u << 16); }
__device__ __forceinline__ float bfhi(unsigned u) { return __uint_as_float(u & 0xFFFF0000u); }

// ============================ sub-bucket histogram ===========================
__global__ __launch_bounds__(256) void hist_kernel(const int* __restrict__ rows,
                                                   int* __restrict__ counts) {
    __shared__ int sh[NCB];
    for (int i = threadIdx.x; i < NCB; i += 256) sh[i] = 0;
    __syncthreads();
    int stride = gridDim.x * blockDim.x;
    const int4* rows4 = (const int4*)rows;
    for (int i = blockIdx.x * blockDim.x + threadIdx.x; i < NNZ / 4; i += stride) {
        int4 r = rows4[i];
        atomicAdd(&sh[r.x >> 8], 1);
        atomicAdd(&sh[r.y >> 8], 1);
        atomicAdd(&sh[r.z >> 8], 1);
        atomicAdd(&sh[r.w >> 8], 1);
    }
    __syncthreads();
    for (int i = threadIdx.x; i < NCB; i += 256)
        if (sh[i]) atomicAdd(&counts[i], sh[i]);
}

// exclusive scan over NCB counts -> boffs + bcursor; cursor1 (super-bucket
// bases) derived from the same scan; offs[NTOT]=NNZ.
__global__ void scan_kernel(const int* __restrict__ counts, int* __restrict__ boffs,
                            int* __restrict__ bcursor, int* __restrict__ cursor1,
                            int* __restrict__ offs) {
    __shared__ int sm[1024];
    int t = threadIdx.x;
    int c = (t < NCB) ? counts[t] : 0;
    sm[t] = c; __syncthreads();
    for (int off = 1; off < 1024; off <<= 1) {
        int v = (t >= off) ? sm[t - off] : 0;
        __syncthreads();
        sm[t] += v;
        __syncthreads();
    }
    if (t < NCB) { boffs[t] = sm[t] - c; bcursor[t] = sm[t] - c; }
    if (t == 1023) { boffs[NCB] = sm[1023]; offs[NTOT] = sm[1023]; }
    if (t < NSUP) cursor1[t] = sm[16 * t] - counts[16 * t];   // = boffs[16t]
}

// ===================== stage-1 partition: 62 super-buckets ===================
// 1024 blocks x ~4884 edges. Runs ~79 edges (632 B); 62 open lines per block,
// each fills after ~1 block iteration -> write-combining succeeds. SoA output.
__global__ __launch_bounds__(256) void part1(
        const int* __restrict__ rows, const int* __restrict__ cols,
        const float* __restrict__ vals, int* __restrict__ cursor1,
        int* __restrict__ exA, int* __restrict__ valA) {
    __shared__ int cnt[NSUP];
    __shared__ int base[NSUP];
    int t = threadIdx.x;
    int tb = blockIdx.x * T1;
    int n = NNZ - tb; if (n <= 0) return; if (n > T1) n = T1;   // n % 4 == 0 always
    if (t < NSUP) cnt[t] = 0;
    __syncthreads();
    for (int i = t * 4; i < n; i += 1024) {          // pass A: count (int4)
        int4 r = *(const int4*)(rows + tb + i);
        atomicAdd(&cnt[r.x >> 12], 1);
        atomicAdd(&cnt[r.y >> 12], 1);
        atomicAdd(&cnt[r.z >> 12], 1);
        atomicAdd(&cnt[r.w >> 12], 1);
    }
    __syncthreads();
    if (t < NSUP) {                                  // claim contiguous runs
        int c = cnt[t];
        base[t] = c ? atomicAdd(&cursor1[t], c) : 0;
        cnt[t] = 0;                                  // reuse as rank cursor
    }
    __syncthreads();
    for (int i = t; i < n; i += 256) {               // pass B: rank + write
        int r = rows[tb + i];
        int s = r >> 12;
        int rank = atomicAdd(&cnt[s], 1);
        int p = base[s] + rank;
        exA[p]  = cols[tb + i] | ((r & 4095) << 18); // col 0..17 | lr12 18..29
        valA[p] = __float_as_int(vals[tb + i]);
    }
}

// ============== stage-2 partition: 16 sub-buckets per super-bucket ===========
// 62x16 blocks; each handles ~1/16 of one super-bucket (~5K edges). 16 open
// lines per block, each fills after ~128 edges processed.
__global__ __launch_bounds__(256) void part2(
        const int* __restrict__ boffs, int* __restrict__ bcursor,
        const int* __restrict__ exA, const int* __restrict__ valA,
        int2* __restrict__ epk) {
    __shared__ int cnt[16], base[16], cur[16];
    int b = blockIdx.x;
    int s = b >> 4, k = b & 15;
    int t = threadIdx.x;
    int sb0 = s * 16;
    int nsb = NCB - sb0; if (nsb > 16) nsb = 16;
    int beg = boffs[sb0];
    int end = boffs[sb0 + nsb];
    int n = end - beg;
    int chunk = (n + G2 - 1) / G2;
    int cb = beg + k * chunk;
    int ce = cb + chunk; if (ce > end) ce = end;
    if (cb >= ce) return;                            // uniform within block
    if (t < 16) cnt[t] = 0;
    __syncthreads();
    for (int i = cb + t; i < ce; i += 256)           // pass A: count
        atomicAdd(&cnt[(exA[i] >> 26) & 15], 1);
    __syncthreads();
    if (t < 16) {                                    // claim runs in sub-bucket space
        int c = cnt[t];
        base[t] = c ? atomicAdd(&bcursor[sb0 + t], c) : 0;
        cur[t] = 0;
    }
    __syncthreads();
    for (int i = cb + t; i < ce; i += 256) {         // pass B: rank + write
        int ex = exA[i];
        int j = (ex >> 26) & 15;
        int rank = atomicAdd(&cur[j], 1);
        int lr8 = (ex >> 18) & 255;
        epk[base[j] + rank] = make_int2((ex & 0x3FFFF) | (lr8 << 18), valA[i]);
    }
}

// ============== per-sub-bucket in-LDS row sort + CSR offsets =================
__global__ __launch_bounds__(256) void bucket_sort(const int* __restrict__ boffs,
                                                   int2* __restrict__ epk,
                                                   int* __restrict__ offs) {
    __shared__ int2 se[SCAP];         // 48 KB
    __shared__ int cnt[256];
    __shared__ int base[256];
    __shared__ int cur[256];
    int b = blockIdx.x, t = threadIdx.x;
    int beg = boffs[b], end = boffs[b + 1];
    int n = end - beg; if (n > SCAP) n = SCAP;   // +14 sigma, unreachable
    cnt[t] = 0;
    __syncthreads();
    for (int i = t; i < n; i += 256) {
        int2 e = epk[beg + i];
        se[i] = e;
        atomicAdd(&cnt[(((unsigned)e.x) >> 18) & 0xFFu], 1);
    }
    __syncthreads();
    int c = cnt[t];
    base[t] = c; __syncthreads();
    for (int off = 1; off < 256; off <<= 1) {     // Hillis-Steele inclusive
        int v = (t >= off) ? base[t - off] : 0;
        __syncthreads();
        base[t] += v;
        __syncthreads();
    }
    int mybase = beg + base[t] - c;               // exclusive + global base
    cur[t] = mybase;
    int r = b * 256 + t;
    if (r < NTOT) offs[r] = mybase;
    __syncthreads();
    for (int i = t; i < n; i += 256) {
        int2 e = se[i];
        int lr = (int)((((unsigned)e.x) >> 18) & 0xFFu);
        int p = atomicAdd(&cur[lr], 1);
        epk[p] = make_int2((int)(((unsigned)e.x) & 0x3FFFFu), e.y);
    }
}

// ===================== convert: ego f32 -> bf16 xb, + pass-throughs =========
__global__ __launch_bounds__(256) void convert_kernel(
        const float* __restrict__ ue, const float* __restrict__ ie,
        const float* __restrict__ up, const float* __restrict__ ip,
        ushort* __restrict__ xb, float* __restrict__ out) {
    const int NG = NROW_ELEMS / 8;               // 2,000,000 8-elem groups
    int g = blockIdx.x * blockDim.x + threadIdx.x;
    if (g < NG) {
        int base = g * 8;
        const float* src = (base < USER_NUM * EMB) ? ue + base
                                                   : ie + (base - USER_NUM * EMB);
        float4 a = ((const float4*)src)[0];
        float4 b = ((const float4*)src)[1];
        float4* oc = (float4*)(out + NROW_ELEMS + base);
        oc[0] = a; oc[1] = b;
        uint4 w;
        w.x = pkbf(a.x, a.y); w.y = pkbf(a.z, a.w);
        w.z = pkbf(b.x, b.y); w.w = pkbf(b.z, b.w);
        ((uint4*)xb)[g] = w;
    } else {
        int pj = (g - NG) * 8;
        if (pj < PROTO_ELEMS) {
            float4 a = *(const float4*)(up + pj), b = *(const float4*)(up + pj + 4);
            float4* o = (float4*)(out + 2 * NROW_ELEMS + pj);
            o[0] = a; o[1] = b;
        } else if (pj < 2 * PROTO_ELEMS) {
            int q = pj - PROTO_ELEMS;
            float4 a = *(const float4*)(ip + q), b = *(const float4*)(ip + q + 4);
            float4* o = (float4*)(out + 2 * NROW_ELEMS + PROTO_ELEMS + q);
            o[0] = a; o[1] = b;
        }
    }
}

// ===================== bf16-gather CSR SpMM (no atomics) =====================
__device__ __forceinline__ void acc8(float* acc, float v, uint4 u) {
    acc[0] += v * bflo(u.x); acc[1] += v * bfhi(u.x);
    acc[2] += v * bflo(u.y); acc[3] += v * bfhi(u.y);
    acc[4] += v * bflo(u.z); acc[5] += v * bfhi(u.z);
    acc[6] += v * bflo(u.w); acc[7] += v * bfhi(u.w);
}

template <int LAYER>
__global__ __launch_bounds__(256) void spmm_bf(
        const ushort* __restrict__ xb,       // gather source (bf16, NTOT*64)
        const int* __restrict__ offs, const int2* __restrict__ epk,
        ushort* __restrict__ lb,             // layer output (bf16), LAYER 1/2
        const float* __restrict__ ue, const float* __restrict__ ie,   // LAYER 3
        const ushort* __restrict__ l1b, const ushort* __restrict__ l2b,// LAYER 3
        float* __restrict__ out) {           // LAYER 3
    int t = blockIdx.x * blockDim.x + threadIdx.x;
    int r = t >> 3, l = t & 7;
    if (r >= NTOT) return;
    const uint4* src = (const uint4*)xb;     // 8 uint4 per row
    int beg = offs[r], end = offs[r + 1];
    float acc[8] = {0.f, 0.f, 0.f, 0.f, 0.f, 0.f, 0.f, 0.f};
    int j = beg;
    for (; j + 3 < end; j += 4) {
        int2 e0 = epk[j], e1 = epk[j + 1], e2 = epk[j + 2], e3 = epk[j + 3];
        uint4 u0 = src[e0.x * 8 + l];
        uint4 u1 = src[e1.x * 8 + l];
        uint4 u2 = src[e2.x * 8 + l];
        uint4 u3 = src[e3.x * 8 + l];
        acc8(acc, __int_as_float(e0.y), u0);
        acc8(acc, __int_as_float(e1.y), u1);
        acc8(acc, __int_as_float(e2.y), u2);
        acc8(acc, __int_as_float(e3.y), u3);
    }
    for (; j < end; ++j) {
        int2 e0 = epk[j];
        uint4 u0 = src[e0.x * 8 + l];
        acc8(acc, __int_as_float(e0.y), u0);
    }
    int idx = r * 8 + l;                     // uint4 index into bf16 row space
    if (LAYER == 1 || LAYER == 2) {
        uint4 w;
        w.x = pkbf(acc[0], acc[1]); w.y = pkbf(acc[2], acc[3]);
        w.z = pkbf(acc[4], acc[5]); w.w = pkbf(acc[6], acc[7]);
        ((uint4*)lb)[idx] = w;
    } else {
        int base = r * EMB + l * 8;          // float index
        const float* ep = (r < USER_NUM) ? ue + base
                                         : ie + (base - USER_NUM * EMB);
        float4 ea = ((const float4*)ep)[0];
        float4 eb = ((const float4*)ep)[1];
        uint4 u1 = ((const uint4*)l1b)[idx];
        uint4 u2 = ((const uint4*)l2b)[idx];
        float4 o0, o1;
        o0.x = (ea.x + bflo(u1.x) + bflo(u2.x) + acc[0]) * 0.25f;
        o0.y = (ea.y + bfhi(u1.x) + bfhi(u2.x) + acc[1]) * 0.25f;
        o0.z = (ea.z + bflo(u1.y) + bflo(u2.y) + acc[2]) * 0.25f;
        o0.w = (ea.w + bfhi(u1.y) + bfhi(u2.y) + acc[3]) * 0.25f;
        o1.x = (eb.x + bflo(u1.z) + bflo(u2.z) + acc[4]) * 0.25f;
        o1.y = (eb.y + bfhi(u1.z) + bfhi(u2.z) + acc[5]) * 0.25f;
        o1.z = (eb.z + bflo(u1.w) + bflo(u2.w) + acc[6]) * 0.25f;
        o1.w = (eb.w + bfhi(u1.w) + bfhi(u2.w) + acc[7]) * 0.25f;
        float4* op = (float4*)(out + base);
        op[0] = o0; op[1] = o1;
    }
}

// =============================================================================
extern "C" void kernel_launch(void* const* d_in, const int* in_sizes, int n_in,
                              void* d_out, int out_size, void* d_ws, size_t ws_size,
                              hipStream_t stream) {
    const float* ue   = (const float*)d_in[0];
    const float* ie   = (const float*)d_in[1];
    const float* up   = (const float*)d_in[2];
    const float* ip   = (const float*)d_in[3];
    const float* vals = (const float*)d_in[4];
    const int*   rows = (const int*)d_in[5];
    const int*   cols = (const int*)d_in[6];
    float* out = (float*)d_out;

    // ws layout (4-byte units):
    //   [0, 5M)         exA     : stage-1 packed keys (20 MB)   } dead after part2;
    //   [5M, 10M)       valA    : stage-1 vals (20 MB)          } region reused by
    //   [0, 8M)         xb      : bf16 ego (32 MB), also l2b    } xb/l1b afterwards
    //   [8M, 16M)       l1b     : bf16 layer-1 (32 MB)
    //   [16M, 26M)      epk     : 5M int2 edges (40 MB)
    //   26,000,000      offs    : NTOT+1 row offsets
    //   26,250,112      boffs   : NCB+1
    //   26,252,000      bcursor : NCB
    //   26,253,000      bcounts : NCB
    //   26,254,000      cursor1 : NSUP
    int*    exA    = (int*)d_ws;
    int*    valA   = (int*)d_ws + 5000000;
    ushort* xb     = (ushort*)d_ws;                  // also l2b (dead after spmm1)
    ushort* l1b    = (ushort*)((int*)d_ws + 8000000);
    int2*   epk    = (int2*)((int*)d_ws + 16000000);
    int*    offs   = (int*)d_ws + 26000000;
    int*    boffs  = (int*)d_ws + 26250112;
    int*    bcursor= (int*)d_ws + 26252000;
    int*    bcounts= (int*)d_ws + 26253000;
    int*    cursor1= (int*)d_ws + 26254000;
    ushort* l2b    = xb;

    const int sgrid = (NTOT * 8 + 255) / 256;        // 7813
    const int cgrid = (NROW_ELEMS / 8 + 2 * PROTO_ELEMS / 8 + 255) / 256;

    // ---- build row-sorted CSR (two-stage partition + LDS sort) ----
    hipMemsetAsync(bcounts, 0, NCB * sizeof(int), stream);
    hist_kernel<<<256, 256, 0, stream>>>(rows, bcounts);
    scan_kernel<<<1, 1024, 0, stream>>>(bcounts, boffs, bcursor, cursor1, offs);
    part1      <<<NSB1, 256, 0, stream>>>(rows, cols, vals, cursor1, exA, valA);
    part2      <<<NSUP * G2, 256, 0, stream>>>(boffs, bcursor, exA, valA, epk);
    bucket_sort<<<NCB, 256, 0, stream>>>(boffs, epk, offs);

    // ---- convert ego to bf16 + all f32 pass-through copies ----
    convert_kernel<<<cgrid, 256, 0, stream>>>(ue, ie, up, ip, xb, out);

    // ---- 3 bf16-gather SpMM layers; f32 assembly in layer 3 ----
    spmm_bf<1><<<sgrid, 256, 0, stream>>>(xb,  offs, epk, l1b,
                                          nullptr, nullptr, nullptr, nullptr, nullptr);
    spmm_bf<2><<<sgrid, 256, 0, stream>>>(l1b, offs, epk, l2b,
                                          nullptr, nullptr, nullptr, nullptr, nullptr);
    spmm_bf<3><<<sgrid, 256, 0, stream>>>(l2b, offs, epk, nullptr,
                                          ue, ie, l1b, l2b, out);
}